// Round 14
// baseline (603.691 us; speedup 1.0000x reference)
//
#include <hip/hip_runtime.h>
#include <hip/hip_bf16.h>
#include <stdint.h>

#define N_NODES 100000
#define N_EDGES 6400000

#define NPB 128                                   // dst nodes per bucket
#define NBKT 782                                  // ceil(100000/128)
#define CAP 10752                                 // records/bucket stride (mult of 4)
#define BIN_CHUNK 12800                           // 500 blocks = balanced 2/CU
#define BIN_THREADS 1024
#define NBIN_BLOCKS (N_EDGES / BIN_CHUNK)         // 500 exactly

// clang ext-vector for 16B index loads
typedef unsigned __attribute__((ext_vector_type(4))) uv4;

// perm1 record: src (bits 0..16) | dstLocal (bits 17..23) | bktLow8 (bits 24..31)
//
// Session facts driving this structure:
//  R9/R10: device-wide sw barriers cost ~0.23us/block/barrier -> fusion dead.
//  R10-R13: layer gathers are request-rate-bound (~3.5cy/divergent line/CU);
//           TLP, ILP and cache-policy (nt) changes are null or negative.
//  R14: gather count is the floor -> remove k_sort from the serial chain
//       instead. Layers consume bucket-sorted perm1 directly via LDS-atomic
//       accumulators (lgkm pipe, overlapped with vmcnt-bound gathers).

// ---------------------------------------------------------------------------
// Bin edges by dst bucket — zero per-record register state (R6/R7-proven;
// R13 balance: 500 blocks).
__global__ __launch_bounds__(1024) void k_bin(const void* __restrict__ ei,
                                              int* __restrict__ gcur,
                                              unsigned* __restrict__ perm1) {
  __shared__ unsigned staging[BIN_CHUNK];          // 51.2 KB -> 2 blocks/CU
  __shared__ int lcnt[1024];                       // counts -> placement cursor
  __shared__ int combo[1024];                      // gbase - excl
  __shared__ int wsum[16];
  __shared__ int s_tot;
  __shared__ int s_th[3];
  __shared__ int s_is64;
  int t = threadIdx.x;
  lcnt[t] = 0;
  if (t < 64) {
    unsigned hv = ((const unsigned*)ei)[2 * t + 1];
    unsigned long long m = __ballot(hv != 0u);
    if (t == 0) s_is64 = (m == 0ull);
  }
  __syncthreads();
  int is64 = s_is64;
  size_t e0 = (size_t)blockIdx.x * BIN_CHUNK;
  int n = BIN_CHUNK;                               // 500 * 12800 == N_EDGES

  // ---- phase A: histogram from dst array only ----
  if (is64) {
    const long long* e = (const long long*)ei;
    for (int k = 2 * t; k < n; k += 2048) {
      uv4 dp = *(const uv4*)(e + (size_t)N_EDGES + e0 + k);
      if (dp.x < N_NODES) atomicAdd(&lcnt[dp.x >> 7], 1);
      if (dp.z < N_NODES) atomicAdd(&lcnt[dp.z >> 7], 1);
    }
  } else {
    const unsigned* e = (const unsigned*)ei;
    for (int k = 4 * t; k < n; k += 4096) {
      uv4 dq = *(const uv4*)(e + (size_t)N_EDGES + e0 + k);
      if (dq.x < N_NODES) atomicAdd(&lcnt[dq.x >> 7], 1);
      if (dq.y < N_NODES) atomicAdd(&lcnt[dq.y >> 7], 1);
      if (dq.z < N_NODES) atomicAdd(&lcnt[dq.z >> 7], 1);
      if (dq.w < N_NODES) atomicAdd(&lcnt[dq.w >> 7], 1);
    }
  }
  __syncthreads();
  // ---- phase B: scan 1024 bins (1 per thread) + global reservation ----
  int c = lcnt[t];
  int lane = t & 63, w = t >> 6;
  int incl = c;
#pragma unroll
  for (int o = 1; o < 64; o <<= 1) {
    int u = __shfl_up(incl, o);
    if (lane >= o) incl += u;
  }
  if (lane == 63) wsum[w] = incl;
  __syncthreads();
  int wb = 0;
  for (int i = 0; i < w; ++i) wb += wsum[i];
  int excl = wb + incl - c;
  int gb = c ? atomicAdd(&gcur[t], c) : 0;
  lcnt[t] = excl;                       // placement cursor
  combo[t] = gb - excl;
  if (t == 256) s_th[0] = excl;
  if (t == 512) s_th[1] = excl;
  if (t == 768) s_th[2] = excl;
  if (t == 1023) s_tot = excl + c;
  __syncthreads();
  // ---- phase C: re-read edges, place via returning cursor atomic ----
  if (is64) {
    const long long* e = (const long long*)ei;
    for (int k = 2 * t; k < n; k += 2048) {
      uv4 sp = *(const uv4*)(e + e0 + k);
      uv4 dp = *(const uv4*)(e + (size_t)N_EDGES + e0 + k);
      if (sp.x < N_NODES && dp.x < N_NODES) {
        int p = atomicAdd(&lcnt[dp.x >> 7], 1);
        staging[p] = sp.x | ((dp.x & (NPB - 1u)) << 17) | (((dp.x >> 7) & 255u) << 24);
      }
      if (sp.z < N_NODES && dp.z < N_NODES) {
        int p = atomicAdd(&lcnt[dp.z >> 7], 1);
        staging[p] = sp.z | ((dp.z & (NPB - 1u)) << 17) | (((dp.z >> 7) & 255u) << 24);
      }
    }
  } else {
    const unsigned* e = (const unsigned*)ei;
    for (int k = 4 * t; k < n; k += 4096) {
      uv4 sq = *(const uv4*)(e + e0 + k);
      uv4 dq = *(const uv4*)(e + (size_t)N_EDGES + e0 + k);
      if (sq.x < N_NODES && dq.x < N_NODES) {
        int p = atomicAdd(&lcnt[dq.x >> 7], 1);
        staging[p] = sq.x | ((dq.x & (NPB - 1u)) << 17) | (((dq.x >> 7) & 255u) << 24);
      }
      if (sq.y < N_NODES && dq.y < N_NODES) {
        int p = atomicAdd(&lcnt[dq.y >> 7], 1);
        staging[p] = sq.y | ((dq.y & (NPB - 1u)) << 17) | (((dq.y >> 7) & 255u) << 24);
      }
      if (sq.z < N_NODES && dq.z < N_NODES) {
        int p = atomicAdd(&lcnt[dq.z >> 7], 1);
        staging[p] = sq.z | ((dq.z & (NPB - 1u)) << 17) | (((dq.z >> 7) & 255u) << 24);
      }
      if (sq.w < N_NODES && dq.w < N_NODES) {
        int p = atomicAdd(&lcnt[dq.w >> 7], 1);
        staging[p] = sq.w | ((dq.w & (NPB - 1u)) << 17) | (((dq.w >> 7) & 255u) << 24);
      }
    }
  }
  __syncthreads();
  // ---- phase D: writeout ----
  int tot = s_tot, th0 = s_th[0], th1 = s_th[1], th2 = s_th[2];
  for (int j = t; j < tot; j += 1024) {
    unsigned r = staging[j];
    int hi = (j >= th0) + (j >= th1) + (j >= th2);
    int b = (int)(r >> 24) | (hi << 8);
    int o = combo[b] + j;
    if (o < CAP) perm1[(size_t)b * CAP + o] = r;
  }
}

// ---------------------------------------------------------------------------
// Per-bucket degree histogram -> dinv only (replaces k_sort; 26MB read,
// no write-back of permuted records).
__global__ __launch_bounds__(256) void k_deg(const int* __restrict__ gcur,
                                             const unsigned* __restrict__ perm1,
                                             float* __restrict__ dinv) {
  __shared__ int h[NPB];
  int b = blockIdx.x, t = threadIdx.x;
  if (t < NPB) h[t] = 0;
  __syncthreads();
  int cnt = min(gcur[b], CAP);
  int base = b * CAP;
  for (int j = 4 * t; j < cnt; j += 1024) {      // uint4 loads, 16B/thread
    uv4 q = *(const uv4*)(perm1 + base + j);     // j+3 <= CAP-1: in-bounds
    atomicAdd(&h[(q.x >> 17) & (NPB - 1)], 1);
    if (j + 1 < cnt) atomicAdd(&h[(q.y >> 17) & (NPB - 1)], 1);
    if (j + 2 < cnt) atomicAdd(&h[(q.z >> 17) & (NPB - 1)], 1);
    if (j + 3 < cnt) atomicAdd(&h[(q.w >> 17) & (NPB - 1)], 1);
  }
  __syncthreads();
  if (t < NPB) {
    int node = b * NPB + t;
    if (node < N_NODES) {
      float dd = (float)h[t] + 1.0f;
      float y = rsqrtf(dd);
      y = y * (1.5f - 0.5f * dd * y * y);
      dinv[node] = y;
    }
  }
}

// ---------------------------------------------------------------------------
// hs1 = dinv * (x @ W1).  One wave per node.
__global__ __launch_bounds__(256) void k_mm1(const float* __restrict__ x,
                                             const float* __restrict__ W1,
                                             const float* __restrict__ dinv,
                                             float* __restrict__ hs1) {
  int gid = blockIdx.x * blockDim.x + threadIdx.x;
  int node = gid >> 6;
  int lane = threadIdx.x & 63;
  if (node >= N_NODES) return;
  float2 v = ((const float2*)x)[(size_t)node * 64 + lane];
  float4 w0 = ((const float4*)W1)[2 * lane];
  float4 w1 = ((const float4*)W1)[2 * lane + 1];
  float a0 = v.x * w0.x + v.y * w1.x;
  float a1 = v.x * w0.y + v.y * w1.y;
  float a2 = v.x * w0.z + v.y * w1.z;
  float a3 = v.x * w0.w + v.y * w1.w;
#pragma unroll
  for (int off = 32; off > 0; off >>= 1) {
    a0 += __shfl_down(a0, off);
    a1 += __shfl_down(a1, off);
    a2 += __shfl_down(a2, off);
    a3 += __shfl_down(a3, off);
  }
  if (lane == 0) {
    float d = dinv[node];
    ((float4*)hs1)[node] = make_float4(d * a0, d * a1, d * a2, d * a3);
  }
}

// ---------------------------------------------------------------------------
// Layer kernels: one block per bucket, LDS float accumulators per dstLocal.
// Gathers (vmcnt pipe) overlap LDS atomics (lgkm pipe). Epilogue is
// reduce-free: thread t<128 owns node b*128+t; writes fully coalesced.

__global__ __launch_bounds__(256) void k_l1(const int* __restrict__ gcur,
                                            const unsigned* __restrict__ perm1,
                                            const float* __restrict__ hs1,
                                            const float* __restrict__ dinv,
                                            const float* __restrict__ W2,
                                            const float* __restrict__ b1,
                                            float* __restrict__ hs2) {
  __shared__ float acc[NPB * 4];                  // 2 KB
  int b = blockIdx.x, t = threadIdx.x;
  acc[t] = 0.f; acc[t + 256] = 0.f;
  __syncthreads();
  int cnt = min(gcur[b], CAP);
  int base = b * CAP;
  for (int j = 4 * t; j < cnt; j += 1024) {
    uv4 q = *(const uv4*)(perm1 + base + j);
    {
      float4 v = ((const float4*)hs1)[q.x & 0x1FFFFu];
      int dl = (q.x >> 17) & (NPB - 1);
      atomicAdd(&acc[4 * dl + 0], v.x); atomicAdd(&acc[4 * dl + 1], v.y);
      atomicAdd(&acc[4 * dl + 2], v.z); atomicAdd(&acc[4 * dl + 3], v.w);
    }
    if (j + 1 < cnt) {
      float4 v = ((const float4*)hs1)[q.y & 0x1FFFFu];
      int dl = (q.y >> 17) & (NPB - 1);
      atomicAdd(&acc[4 * dl + 0], v.x); atomicAdd(&acc[4 * dl + 1], v.y);
      atomicAdd(&acc[4 * dl + 2], v.z); atomicAdd(&acc[4 * dl + 3], v.w);
    }
    if (j + 2 < cnt) {
      float4 v = ((const float4*)hs1)[q.z & 0x1FFFFu];
      int dl = (q.z >> 17) & (NPB - 1);
      atomicAdd(&acc[4 * dl + 0], v.x); atomicAdd(&acc[4 * dl + 1], v.y);
      atomicAdd(&acc[4 * dl + 2], v.z); atomicAdd(&acc[4 * dl + 3], v.w);
    }
    if (j + 3 < cnt) {
      float4 v = ((const float4*)hs1)[q.w & 0x1FFFFu];
      int dl = (q.w >> 17) & (NPB - 1);
      atomicAdd(&acc[4 * dl + 0], v.x); atomicAdd(&acc[4 * dl + 1], v.y);
      atomicAdd(&acc[4 * dl + 2], v.z); atomicAdd(&acc[4 * dl + 3], v.w);
    }
  }
  __syncthreads();
  if (t < NPB) {
    int node = b * NPB + t;
    if (node < N_NODES) {
      float dn = dinv[node];
      float4 hl = ((const float4*)hs1)[node];
      float t0 = tanhf(dn * (acc[4 * t + 0] + hl.x) + b1[0]);
      float t1 = tanhf(dn * (acc[4 * t + 1] + hl.y) + b1[1]);
      float t2 = tanhf(dn * (acc[4 * t + 2] + hl.z) + b1[2]);
      float t3 = tanhf(dn * (acc[4 * t + 3] + hl.w) + b1[3]);
      float4 r;
      r.x = dn * (t0 * W2[0] + t1 * W2[4] + t2 * W2[8]  + t3 * W2[12]);
      r.y = dn * (t0 * W2[1] + t1 * W2[5] + t2 * W2[9]  + t3 * W2[13]);
      r.z = dn * (t0 * W2[2] + t1 * W2[6] + t2 * W2[10] + t3 * W2[14]);
      r.w = dn * (t0 * W2[3] + t1 * W2[7] + t2 * W2[11] + t3 * W2[15]);
      ((float4*)hs2)[node] = r;
    }
  }
}

__global__ __launch_bounds__(256) void k_l2(const int* __restrict__ gcur,
                                            const unsigned* __restrict__ perm1,
                                            const float* __restrict__ hs2,
                                            const float* __restrict__ dinv,
                                            const float* __restrict__ W3,
                                            const float* __restrict__ b2,
                                            float* __restrict__ hs3) {
  __shared__ float acc[NPB * 4];
  int b = blockIdx.x, t = threadIdx.x;
  acc[t] = 0.f; acc[t + 256] = 0.f;
  __syncthreads();
  int cnt = min(gcur[b], CAP);
  int base = b * CAP;
  for (int j = 4 * t; j < cnt; j += 1024) {
    uv4 q = *(const uv4*)(perm1 + base + j);
    {
      float4 v = ((const float4*)hs2)[q.x & 0x1FFFFu];
      int dl = (q.x >> 17) & (NPB - 1);
      atomicAdd(&acc[4 * dl + 0], v.x); atomicAdd(&acc[4 * dl + 1], v.y);
      atomicAdd(&acc[4 * dl + 2], v.z); atomicAdd(&acc[4 * dl + 3], v.w);
    }
    if (j + 1 < cnt) {
      float4 v = ((const float4*)hs2)[q.y & 0x1FFFFu];
      int dl = (q.y >> 17) & (NPB - 1);
      atomicAdd(&acc[4 * dl + 0], v.x); atomicAdd(&acc[4 * dl + 1], v.y);
      atomicAdd(&acc[4 * dl + 2], v.z); atomicAdd(&acc[4 * dl + 3], v.w);
    }
    if (j + 2 < cnt) {
      float4 v = ((const float4*)hs2)[q.z & 0x1FFFFu];
      int dl = (q.z >> 17) & (NPB - 1);
      atomicAdd(&acc[4 * dl + 0], v.x); atomicAdd(&acc[4 * dl + 1], v.y);
      atomicAdd(&acc[4 * dl + 2], v.z); atomicAdd(&acc[4 * dl + 3], v.w);
    }
    if (j + 3 < cnt) {
      float4 v = ((const float4*)hs2)[q.w & 0x1FFFFu];
      int dl = (q.w >> 17) & (NPB - 1);
      atomicAdd(&acc[4 * dl + 0], v.x); atomicAdd(&acc[4 * dl + 1], v.y);
      atomicAdd(&acc[4 * dl + 2], v.z); atomicAdd(&acc[4 * dl + 3], v.w);
    }
  }
  __syncthreads();
  if (t < NPB) {
    int node = b * NPB + t;
    if (node < N_NODES) {
      float dn = dinv[node];
      float4 hl = ((const float4*)hs2)[node];
      float t0 = tanhf(dn * (acc[4 * t + 0] + hl.x) + b2[0]);
      float t1 = tanhf(dn * (acc[4 * t + 1] + hl.y) + b2[1]);
      float t2 = tanhf(dn * (acc[4 * t + 2] + hl.z) + b2[2]);
      float t3 = tanhf(dn * (acc[4 * t + 3] + hl.w) + b2[3]);
      float2 r;
      r.x = dn * (t0 * W3[0] + t1 * W3[2] + t2 * W3[4] + t3 * W3[6]);
      r.y = dn * (t0 * W3[1] + t1 * W3[3] + t2 * W3[5] + t3 * W3[7]);
      ((float2*)hs3)[node] = r;
    }
  }
}

__global__ __launch_bounds__(256) void k_l3(const int* __restrict__ gcur,
                                            const unsigned* __restrict__ perm1,
                                            const float* __restrict__ hs3,
                                            const float* __restrict__ dinv,
                                            const float* __restrict__ Wc,
                                            const float* __restrict__ bc,
                                            const float* __restrict__ b3,
                                            float* __restrict__ out) {
  __shared__ float acc[NPB * 2];                  // 1 KB
  int b = blockIdx.x, t = threadIdx.x;
  acc[t] = 0.f;                                   // 256 covers 128*2
  __syncthreads();
  int cnt = min(gcur[b], CAP);
  int base = b * CAP;
  for (int j = 4 * t; j < cnt; j += 1024) {
    uv4 q = *(const uv4*)(perm1 + base + j);
    {
      float2 v = ((const float2*)hs3)[q.x & 0x1FFFFu];
      int dl = (q.x >> 17) & (NPB - 1);
      atomicAdd(&acc[2 * dl + 0], v.x); atomicAdd(&acc[2 * dl + 1], v.y);
    }
    if (j + 1 < cnt) {
      float2 v = ((const float2*)hs3)[q.y & 0x1FFFFu];
      int dl = (q.y >> 17) & (NPB - 1);
      atomicAdd(&acc[2 * dl + 0], v.x); atomicAdd(&acc[2 * dl + 1], v.y);
    }
    if (j + 2 < cnt) {
      float2 v = ((const float2*)hs3)[q.z & 0x1FFFFu];
      int dl = (q.z >> 17) & (NPB - 1);
      atomicAdd(&acc[2 * dl + 0], v.x); atomicAdd(&acc[2 * dl + 1], v.y);
    }
    if (j + 3 < cnt) {
      float2 v = ((const float2*)hs3)[q.w & 0x1FFFFu];
      int dl = (q.w >> 17) & (NPB - 1);
      atomicAdd(&acc[2 * dl + 0], v.x); atomicAdd(&acc[2 * dl + 1], v.y);
    }
  }
  __syncthreads();
  if (t < NPB) {
    int node = b * NPB + t;
    if (node < N_NODES) {
      float dn = dinv[node];
      float2 hl = ((const float2*)hs3)[node];
      float t0 = tanhf(dn * (acc[2 * t + 0] + hl.x) + b3[0]);
      float t1 = tanhf(dn * (acc[2 * t + 1] + hl.y) + b3[1]);
#pragma unroll
      for (int c = 0; c < 10; ++c)
        out[(size_t)node * 10 + c] = t0 * Wc[c] + t1 * Wc[10 + c] + bc[c];
      out[(size_t)N_NODES * 10 + 2 * node + 0] = t0;
      out[(size_t)N_NODES * 10 + 2 * node + 1] = t1;
    }
  }
}

// ---------------------------------------------------------------------------
extern "C" void kernel_launch(void* const* d_in, const int* in_sizes, int n_in,
                              void* d_out, int out_size, void* d_ws, size_t ws_size,
                              hipStream_t stream) {
  const float* x  = (const float*)d_in[0];
  const void*  ei = d_in[1];
  const float* W1 = (const float*)d_in[2];
  const float* b1 = (const float*)d_in[3];
  const float* W2 = (const float*)d_in[4];
  const float* b2 = (const float*)d_in[5];
  const float* W3 = (const float*)d_in[6];
  const float* b3 = (const float*)d_in[7];
  const float* Wc = (const float*)d_in[8];
  const float* bc = (const float*)d_in[9];
  float* out = (float*)d_out;

  const size_t N = N_NODES;
  float* base = (float*)d_ws;
  float* dinv = base;                            // N
  float* hs1  = base + N;                        // 4N
  float* hs2  = base + 5 * N;                    // 4N
  float* hs3  = base + 9 * N;                    // 2N
  int*   gcur = (int*)(base + 13 * N);           // 1024 ints
  unsigned* perm1 = (unsigned*)(base + 13 * N + 2048);   // NBKT*CAP (33.6 MB)

  (void)hipMemsetAsync(gcur, 0, 1024 * sizeof(int), stream);
  k_bin<<<NBIN_BLOCKS, BIN_THREADS, 0, stream>>>(ei, gcur, perm1);
  k_deg<<<NBKT, 256, 0, stream>>>(gcur, perm1, dinv);
  k_mm1<<<(N_NODES * 64) / 256, 256, 0, stream>>>(x, W1, dinv, hs1);

  k_l1<<<NBKT, 256, 0, stream>>>(gcur, perm1, hs1, dinv, W2, b1, hs2);
  k_l2<<<NBKT, 256, 0, stream>>>(gcur, perm1, hs2, dinv, W3, b2, hs3);
  k_l3<<<NBKT, 256, 0, stream>>>(gcur, perm1, hs3, dinv, Wc, bc, b3, out);
}